// Round 25
// baseline (88.043 us; speedup 1.0000x reference)
//
#include <hip/hip_runtime.h>

// VQ-VAE VectorQuantizer forward, fp32, MI355X.
// B=64, C=D=64, H=W=32 -> N=65536 pixels, K=1024 codes.
// Outputs (flat concat): [0] loss, [1..4194305) quantized BCHW, [4194305..) indices (as float)
//
// R25: two zero-risk scheduler levers on the R24 structure (validated, 86.7us):
// (a) T5 s_setprio(1) around the MFMA cluster — 4 independent blocks/CU give
//     wave role-diversity (staging vs MFMA vs epilogue), the regime where
//     setprio pays (+21-39% on phase-split GEMM in learn_hip).
// (b) T1 XCD-aware blockIdx swizzle (1024 blocks % 8 == 0 -> bijective simple
//     form) for x-tile L2 locality. Pure block permutation.
// Everything else EXACTLY R24. MARGIN 8e-5 (R14-24 validated). Exact-path
// arithmetic BIT-IDENTICAL to R0-R24 (passed, absmax 3.8e-6).

#define KCODES 1024
#define DDIM   64
#define NPIX   65536
#define QELEMS 4194304
#define IDX_OFF (1 + QELEMS)
#define MARGIN 8e-5f
#define WT     2           // tiles per window (gemm)
#define NWIN   32          // 64 tiles / 2
#define NB     2           // pixels per cleanup chunk
#define NCLEAN 2048        // cleanup grid / dpart slots

typedef __attribute__((ext_vector_type(8))) short bf16x8;
typedef __attribute__((ext_vector_type(4))) float f32x4;

static __device__ __forceinline__ unsigned short f2bf(float f) {
    unsigned int u = __float_as_uint(f);
    unsigned int r = (u + 0x7FFFu + ((u >> 16) & 1u)) >> 16;   // RNE
    return (unsigned short)r;
}
static __device__ __forceinline__ float bf2f(unsigned short h) {
    return __uint_as_float(((unsigned int)h) << 16);
}

// ---------------- e prep v2: coalesced LDS-staged esq + bf16 split of (-2e) ----------------
// 64 blocks x 256 thr; block bk handles codes [bk*16, bk*16+16).
__global__ void __launch_bounds__(256) esplit_kernel(const float* __restrict__ e,
                                                     float* __restrict__ esq,
                                                     unsigned short* __restrict__ Eh,
                                                     unsigned short* __restrict__ El,
                                                     int* __restrict__ count,
                                                     float* __restrict__ dpart) {
    __shared__ float se[16][64];      // 4KB: 16 codes x 64 dims
    const int tid = threadIdx.x;
    const int bk = blockIdx.x;
    if (bk == 0) {
        if (tid == 0) *count = 0;
        for (int i = tid; i < NCLEAN; i += 256) dpart[i] = 0.f;  // ws poisoned; zero each call
    }

    // stage 16 codes = 4KB with one coalesced float4 per thread
    {
        const float4 v = *(const float4*)(e + (size_t)bk * 1024 + tid * 4);
        const int c = tid >> 4;
        const int d0 = (tid & 15) * 4;
        se[c][d0 + 0] = v.x;
        se[c][d0 + 1] = v.y;
        se[c][d0 + 2] = v.z;
        se[c][d0 + 3] = v.w;
    }
    __syncthreads();

    // esq: threads 0-15, EXACT numpy pairwise-8 from LDS copies (same order)
    if (tid < 16) {
#pragma clang fp contract(off)
        float r[8];
#pragma unroll
        for (int j = 0; j < 8; ++j) { float v = se[tid][j]; r[j] = v * v; }
#pragma unroll
        for (int i = 1; i < 8; ++i) {
#pragma unroll
            for (int j = 0; j < 8; ++j) { float v = se[tid][i * 8 + j]; r[j] += v * v; }
        }
        esq[bk * 16 + tid] = ((r[0] + r[1]) + (r[2] + r[3])) + ((r[4] + r[5]) + (r[6] + r[7]));
    }

    // split of (-2e): thread -> (code c, dchunk d0); packed 8B stores (coalesced)
    {
        const int c = tid >> 4;
        const int d0 = (tid & 15) * 4;
        unsigned short h[4], lo[4];
#pragma unroll
        for (int j = 0; j < 4; ++j) {
            float v = -2.0f * se[c][d0 + j];       // exact scaling
            h[j] = f2bf(v);
            lo[j] = f2bf(v - bf2f(h[j]));
        }
        const size_t off = (size_t)(bk * 16 + c) * DDIM + d0;
        *(ushort4*)(Eh + off) = make_ushort4(h[0], h[1], h[2], h[3]);
        *(ushort4*)(El + off) = make_ushort4(lo[0], lo[1], lo[2], lo[3]);
    }
}

// ---------------- MFMA scores + top-2 + fused compact + fused gather/loss ----------------
// Block = 256 thr = 4 waves; 64 px/block. 2-tile windows, 32 barriers.
// LDS 36.5KB -> 4 blocks/CU; grid 1024 = one packed round. XCD-swizzled blockIdx.
__global__ void __launch_bounds__(256, 4) gemm_kernel(const float* __restrict__ x,
                                                      const float* __restrict__ e,
                                                      const unsigned short* __restrict__ Eh,
                                                      const unsigned short* __restrict__ El,
                                                      const float* __restrict__ esq,
                                                      int* __restrict__ count,
                                                      int* __restrict__ list,
                                                      float* __restrict__ partial,
                                                      float* __restrict__ out) {
    __shared__ float x_lds[DDIM][64];              // 16KB
    __shared__ float esq_lds[KCODES];              // 4KB
    __shared__ unsigned char btile[2][WT][4096];   // 16KB dbuf window (per tile: Eh 2KB | El 2KB)
    __shared__ int sflag[64];
    __shared__ int sidx_l[64];

    const int tid = threadIdx.x;
    const int w = __builtin_amdgcn_readfirstlane(tid >> 6);
    const int l = tid & 63;
    const int g = l >> 4;              // 0..3
    const int col = l & 15;
    // T1: XCD-aware swizzle (1024 % 8 == 0 -> bijective): consecutive swz-ids
    // within an XCD cover contiguous pixel tiles -> x-read L2 locality.
    const int bid = (int)(blockIdx.x & 7) * 128 + (int)(blockIdx.x >> 3);
    const int pxbase = bid * 64;
    const int b = pxbase >> 10;
    const int p0 = pxbase & 1023;

    // stage x tile + esq
    {
        const float* xg = x + (size_t)b * 65536 + p0;
        for (int t = tid; t < DDIM * 64; t += 256)
            x_lds[t >> 6][t & 63] = xg[(size_t)(t >> 6) * 1024 + (t & 63)];
        for (int t = tid; t < KCODES; t += 256)
            esq_lds[t] = esq[t];
    }
    __syncthreads();

    // A fragments: row = col (px_local = w*16+col), k(d)-slot = g*8 + j (+32 per d-half)
    bf16x8 Ah0, Ah1, Al0, Al1;
    {
        const int pxl = w * 16 + col;
#pragma unroll
        for (int j = 0; j < 8; ++j) {
            float v0 = x_lds[g * 8 + j][pxl];
            unsigned short h0 = f2bf(v0);
            Ah0[j] = (short)h0;
            Al0[j] = (short)f2bf(v0 - bf2f(h0));
            float v1 = x_lds[32 + g * 8 + j][pxl];
            unsigned short h1 = f2bf(v1);
            Ah1[j] = (short)h1;
            Al1[j] = (short)f2bf(v1 - bf2f(h1));
        }
    }

    // B staging: thread covers 16B of each 4KB tile; 2 tiles per window.
    // swizzle: dchunk ^= (code&7)<<4 (bijective within each 128B code-row).
    const unsigned short* src_base = (tid < 128) ? Eh : El;
    const int u = tid & 127;
    const int code_w = u >> 3;
    const int dst_off = ((tid >> 7) << 11) + (code_w << 7)
                      + (((u & 7) << 4) ^ ((code_w & 7) << 4));
    float4 s0g, s1g;
    auto LDW = [&](int i) {    // load window i (tiles 2i, 2i+1)
        const char* sb = (const char*)src_base + (size_t)(2 * i) * 2048 + (size_t)u * 16;
        s0g = *(const float4*)(sb);
        s1g = *(const float4*)(sb + 2048);
    };
    auto STW = [&](int i) {
        *(float4*)&btile[i & 1][0][dst_off] = s0g;
        *(float4*)&btile[i & 1][1][dst_off] = s1g;
    };

    const int cx = (col & 7) << 4;
    const int rb = col << 7;
    const int oh0 = rb + ((g << 4) ^ cx);
    const int oh1 = rb + (((g << 4) + 64) ^ cx);

    float m1_0 = 3.4e38f, m1_1 = 3.4e38f, m1_2 = 3.4e38f, m1_3 = 3.4e38f;
    float m2_0 = 3.4e38f, m2_1 = 3.4e38f, m2_2 = 3.4e38f, m2_3 = 3.4e38f;
    int i1_0 = 0, i1_1 = 0, i1_2 = 0, i1_3 = 0;

    LDW(0); STW(0);    // window 0 staged (vmcnt auto before ds_write)
    LDW(1);            // window 1 in flight
    __syncthreads();

#pragma unroll 1
    for (int wn = 0; wn < NWIN; ++wn) {
        if (wn + 1 < NWIN) STW(wn + 1);   // buf (wn+1)&1: reads finished at last barrier
        if (wn + 2 < NWIN) LDW(wn + 2);

        const unsigned char* bw = &btile[wn & 1][0][0];
        const int kbase = wn * 32 + col;

        // 2 tiles, each a single 6-deep MFMA chain, acc seeded with esq.
        // T5: boost wave priority through the MFMA cluster (role-diverse
        // waves across the 4 independent blocks/CU -> scheduler can prefer
        // MFMA-entering waves).
        f32x4 t0, t1;
        __builtin_amdgcn_s_setprio(1);
#define CHAIN(J, ACC)                                                          \
        {                                                                      \
            const unsigned char* bp_ = bw + (J) * 4096;                        \
            const bf16x8 Bh0 = *(const bf16x8*)(bp_ + oh0);                    \
            const bf16x8 Bh1 = *(const bf16x8*)(bp_ + oh1);                    \
            const bf16x8 Bl0 = *(const bf16x8*)(bp_ + 2048 + oh0);             \
            const bf16x8 Bl1 = *(const bf16x8*)(bp_ + 2048 + oh1);             \
            const float qe_ = esq_lds[kbase + (J) * 16];                       \
            ACC = (f32x4){qe_, qe_, qe_, qe_};                                 \
            ACC = __builtin_amdgcn_mfma_f32_16x16x32_bf16(Ah0, Bh0, ACC, 0, 0, 0); \
            ACC = __builtin_amdgcn_mfma_f32_16x16x32_bf16(Al0, Bh0, ACC, 0, 0, 0); \
            ACC = __builtin_amdgcn_mfma_f32_16x16x32_bf16(Ah0, Bl0, ACC, 0, 0, 0); \
            ACC = __builtin_amdgcn_mfma_f32_16x16x32_bf16(Ah1, Bh1, ACC, 0, 0, 0); \
            ACC = __builtin_amdgcn_mfma_f32_16x16x32_bf16(Al1, Bh1, ACC, 0, 0, 0); \
            ACC = __builtin_amdgcn_mfma_f32_16x16x32_bf16(Ah1, Bl1, ACC, 0, 0, 0); \
        }
        CHAIN(0, t0)
        CHAIN(1, t1)
#undef CHAIN
        __builtin_amdgcn_s_setprio(0);

        // exact 2-score top2; ks ascending; strict-< => first-occurrence.
#define WTOP(R, M1, M2, I1)                                                    \
        {                                                                      \
            float s0_ = t0[R], s1_ = t1[R];                                    \
            float p01 = fminf(s0_, s1_), q01 = fmaxf(s0_, s1_);                \
            int i01 = (s1_ < s0_) ? kbase + 16 : kbase;                        \
            M2 = fminf(M2, fminf(q01, fmaxf(M1, p01)));                        \
            if (p01 < M1) I1 = i01;                                            \
            M1 = fminf(M1, p01);                                               \
        }
        WTOP(0, m1_0, m2_0, i1_0)
        WTOP(1, m1_1, m2_1, i1_1)
        WTOP(2, m1_2, m2_2, i1_2)
        WTOP(3, m1_3, m2_3, i1_3)
#undef WTOP
        __syncthreads();
    }

    // cross-lane merge over the 16 lanes of group g; record idx + flag in LDS
#define MERGE(M1, M2, I1, R)                                                   \
    {                                                                          \
        float a1_ = M1, a2_ = M2; int j1 = I1;                                 \
        _Pragma("unroll")                                                      \
        for (int off = 1; off < 16; off <<= 1) {                               \
            float b1 = __shfl_xor(a1_, off);                                   \
            int jb = __shfl_xor(j1, off);                                      \
            float b2 = __shfl_xor(a2_, off);                                   \
            float hi = fmaxf(a1_, b1);                                         \
            a2_ = fminf(fminf(a2_, b2), hi);                                   \
            if (b1 < a1_) j1 = jb;                                             \
            a1_ = fminf(a1_, b1);                                              \
        }                                                                      \
        if (col == 0) {                                                        \
            int pxl = w * 16 + g * 4 + (R);                                    \
            sflag[pxl] = (a2_ <= a1_ + MARGIN) ? 1 : 0;                        \
            sidx_l[pxl] = j1;                                                  \
        }                                                                      \
    }
    MERGE(m1_0, m2_0, i1_0, 0)
    MERGE(m1_1, m2_1, i1_1, 1)
    MERGE(m1_2, m2_2, i1_2, 2)
    MERGE(m1_3, m2_3, i1_3, 3)
#undef MERGE

    __syncthreads();

    // fused compaction + index output (coalesced)
    if (tid < 64) {
        out[IDX_OFF + pxbase + tid] = (float)sidx_l[tid];
        const bool f = sflag[tid] != 0;
        unsigned long long m = __ballot(f);
        int base = 0;
        if (l == 0 && m) base = atomicAdd(count, __popcll(m));
        base = __shfl(base, 0);
        if (f) {
            unsigned long long below = m & ((1ULL << l) - 1ULL);
            list[base + __popcll(below)] = pxbase + tid;
        }
    }

    // fused gather (quantized write) + loss partial (excludes flagged px)
    {
        const int px = tid & 63;
        const int dc = (tid >> 6) << 4;
        const int j1 = sidx_l[px];
        const bool fl = sflag[px] != 0;
        const float* er = e + (size_t)j1 * DDIM + dc;    // exact fp32 row (L2-hot)
        const float4 e0v = *(const float4*)(er);
        const float4 e1v = *(const float4*)(er + 4);
        const float4 e2v = *(const float4*)(er + 8);
        const float4 e3v = *(const float4*)(er + 12);
        float* ob = out + 1 + (((size_t)(b * 64 + dc)) << 10) + p0 + px;
        float acc = 0.f;
#define QW(VV, I0)                                                             \
        {                                                                      \
            ob[(size_t)(I0 + 0) << 10] = VV.x;                                 \
            ob[(size_t)(I0 + 1) << 10] = VV.y;                                 \
            ob[(size_t)(I0 + 2) << 10] = VV.z;                                 \
            ob[(size_t)(I0 + 3) << 10] = VV.w;                                 \
            float d0_ = VV.x - x_lds[dc + I0 + 0][px];                         \
            float d1_ = VV.y - x_lds[dc + I0 + 1][px];                         \
            float d2_ = VV.z - x_lds[dc + I0 + 2][px];                         \
            float d3_ = VV.w - x_lds[dc + I0 + 3][px];                         \
            acc = __builtin_fmaf(d0_, d0_, acc);                               \
            acc = __builtin_fmaf(d1_, d1_, acc);                               \
            acc = __builtin_fmaf(d2_, d2_, acc);                               \
            acc = __builtin_fmaf(d3_, d3_, acc);                               \
        }
        QW(e0v, 0)
        QW(e1v, 4)
        QW(e2v, 8)
        QW(e3v, 12)
#undef QW
        if (fl) acc = 0.f;
        __syncthreads();                 // all x_lds reads done before reuse as reduce buf
        float* red = &x_lds[0][0];
        red[tid] = acc;
        __syncthreads();
        for (int s = 128; s > 0; s >>= 1) {
            if (tid < s) red[tid] += red[tid + s];
            __syncthreads();
        }
        if (tid == 0) partial[bid] = red[0];
    }
}

// ---------------- cleanup: exact argmin, NB=2 px/chunk, grid 2048 (R24) ----------------
__global__ void __launch_bounds__(256, 4) cleanup_kernel(const float* __restrict__ x,
                                                         const float* __restrict__ e,
                                                         const float* __restrict__ esq,
                                                         const int* __restrict__ count,
                                                         const int* __restrict__ list,
                                                         float* __restrict__ dpart,
                                                         float* __restrict__ out) {
    __shared__ float tile[DDIM][257];   // 65.8KB transpose tile
    __shared__ float xs[NB][68];
    __shared__ float xsqs[NB];
    __shared__ float rbest[4];
    __shared__ int   ridx[4];
    __shared__ int   plist[NB];
    __shared__ int   jsel;
    __shared__ float dacc;

    const int tid = threadIdx.x;
    const int cnt = *count;
    const int nchunk = (cnt + NB - 1) / NB;
    if (tid == 0) dacc = 0.f;

    for (int chunk = blockIdx.x; chunk < nchunk; chunk += gridDim.x) {
        const int base = chunk * NB;
        const int np = min(NB, cnt - base);      // block-uniform

        if (tid < np) plist[tid] = list[base + tid];
        __syncthreads();
        for (int q = tid; q < np * 64; q += 256) {
            const int pp = q >> 6, d = q & 63;
            const int p = plist[pp];
            xs[pp][d] = x[(size_t)(p >> 10) * 65536 + (size_t)d * 1024 + (p & 1023)];
        }
        __syncthreads();
        if (tid < np) {
#pragma clang fp contract(off)
            float r[8];
#pragma unroll
            for (int j = 0; j < 8; ++j) { float v = xs[tid][j]; r[j] = v * v; }
#pragma unroll
            for (int ii = 1; ii < 8; ++ii) {
#pragma unroll
                for (int j = 0; j < 8; ++j) { float v = xs[tid][ii * 8 + j]; r[j] += v * v; }
            }
            xsqs[tid] = ((r[0] + r[1]) + (r[2] + r[3])) + ((r[4] + r[5]) + (r[6] + r[7]));
        }

        float best[NB];
        int bidx[NB];
#pragma unroll
        for (int pp = 0; pp < NB; ++pp) { best[pp] = 3.4e38f; bidx[pp] = 0; }

#pragma unroll 1
        for (int T = 0; T < 4; ++T) {
            __syncthreads();
#pragma unroll
            for (int i = 0; i < 16; ++i) {
                const float4 v = *(const float4*)(e + (size_t)T * 16384 + (size_t)i * 1024 + tid * 4);
                const int c = 16 * i + (tid >> 4);
                const int d0 = (4 * tid) & 63;
                tile[d0 + 0][c] = v.x;
                tile[d0 + 1][c] = v.y;
                tile[d0 + 2][c] = v.z;
                tile[d0 + 3][c] = v.w;
            }
            __syncthreads();
            const float qe = esq[T * 256 + tid];
            const int kk = T * 256 + tid;
#pragma unroll
            for (int pp = 0; pp < NB; ++pp) {
                if (pp < np) {
                    float dt = 0.f;
#pragma unroll
                    for (int d = 0; d < DDIM; ++d)
                        dt = __builtin_fmaf(xs[pp][d], tile[d][tid], dt);
                    const float s = (xsqs[pp] - 2.0f * dt) + qe;
                    if (s < best[pp]) { best[pp] = s; bidx[pp] = kk; }
                }
            }
        }

#pragma unroll
        for (int pp = 0; pp < NB; ++pp) {
            if (pp < np) {
                const int p = plist[pp];
                float bb = best[pp];
                int bj = bidx[pp];
#pragma unroll
                for (int off = 1; off < 64; off <<= 1) {
                    float b2 = __shfl_xor(bb, off);
                    int k2 = __shfl_xor(bj, off);
                    if (b2 < bb || (b2 == bb && k2 < bj)) { bb = b2; bj = k2; }
                }
                if ((tid & 63) == 0) { rbest[tid >> 6] = bb; ridx[tid >> 6] = bj; }
                __syncthreads();
                if (tid == 0) {
                    float b0 = rbest[0]; int j0 = ridx[0];
#pragma unroll
                    for (int c2 = 1; c2 < 4; ++c2)
                        if (rbest[c2] < b0 || (rbest[c2] == b0 && ridx[c2] < j0)) {
                            b0 = rbest[c2]; j0 = ridx[c2];
                        }
                    jsel = j0;
                    out[IDX_OFF + p] = (float)j0;
                }
                __syncthreads();
                // patch quantized row + accumulate exact per-pixel contribution
                if (tid < 64) {
                    const int j0 = jsel;
                    const int d = tid;
                    const float ev = e[(size_t)j0 * DDIM + d];
                    const float xv = xs[pp][d];
                    out[1 + (((size_t)((p >> 10) * 64 + d)) << 10) + (p & 1023)] = ev;
                    float df = ev - xv;
                    float c = df * df;
#pragma unroll
                    for (int off = 1; off < 64; off <<= 1)
                        c += __shfl_xor(c, off);
                    if (tid == 0) dacc += c;
                }
                __syncthreads();
            }
        }
        __syncthreads();
    }
    if (tid == 0) dpart[blockIdx.x] = dacc;
}

// ---------------- deterministic loss finalize: 1024 partials + 2048 dparts ----------------
__global__ void __launch_bounds__(256) loss_kernel(const float* __restrict__ partial,
                                                   const float* __restrict__ dpart,
                                                   float* __restrict__ out) {
    float acc = 0.f;
    for (int i = threadIdx.x; i < 1024; i += 256) acc += partial[i];
    for (int i = threadIdx.x; i < NCLEAN; i += 256) acc += dpart[i];
    __shared__ float sm[256];
    sm[threadIdx.x] = acc;
    __syncthreads();
    for (int s = 128; s > 0; s >>= 1) {
        if (threadIdx.x < s) sm[threadIdx.x] += sm[threadIdx.x + s];
        __syncthreads();
    }
    // loss = q_latent + 0.25*e_latent = 1.25 * mean(diff^2)
    if (threadIdx.x == 0) out[0] = sm[0] * (1.25f / 4194304.f);
}

extern "C" void kernel_launch(void* const* d_in, const int* in_sizes, int n_in,
                              void* d_out, int out_size, void* d_ws, size_t ws_size,
                              hipStream_t stream) {
    const float* x = (const float*)d_in[0];   // [64,64,32,32]
    const float* e = (const float*)d_in[1];   // [1024,64]
    float* out = (float*)d_out;

    // ws: esq 4KB | Eh 128KB | El 128KB | count 4KB | list 256KB | partial 4KB | dpart 8KB
    char* wsb = (char*)d_ws;
    float*          esq     = (float*)wsb;
    unsigned short* Eh      = (unsigned short*)(wsb + 4096);
    unsigned short* El      = (unsigned short*)(wsb + 4096 + 131072);
    int*            count   = (int*)(wsb + 4096 + 2 * 131072);
    int*            list    = (int*)(wsb + 4096 + 2 * 131072 + 4096);
    float*          partial = (float*)(wsb + 4096 + 2 * 131072 + 4096 + NPIX * 4);
    float*          dpart   = (float*)(wsb + 4096 + 2 * 131072 + 4096 + NPIX * 4 + 4096);

    esplit_kernel<<<64, 256, 0, stream>>>(e, esq, Eh, El, count, dpart);
    gemm_kernel<<<NPIX / 64, 256, 0, stream>>>(x, e, Eh, El, esq, count, list, partial, out);
    cleanup_kernel<<<NCLEAN, 256, 0, stream>>>(x, e, esq, count, list, dpart, out);
    loss_kernel<<<1, 256, 0, stream>>>(partial, dpart, out);
}

// Round 26
// 86.340 us; speedup vs baseline: 1.0197x; 1.0197x over previous
//
#include <hip/hip_runtime.h>

// VQ-VAE VectorQuantizer forward, fp32, MI355X.
// B=64, C=D=64, H=W=32 -> N=65536 pixels, K=1024 codes.
// Outputs (flat concat): [0] loss, [1..4194305) quantized BCHW, [4194305..) indices (as float)
//
// R26 = R24 exactly (session best, 86.7us). R25's A/B proved setprio+XCD-swizzle
// null-to-negative in this barrier-synced template (setprio needs intra-block
// phase split to pay; swizzle needs HBM-bound regime). Reverted.
// Structure: esplit (coalesced LDS-staged (-2e) bf16-split + exact esq) ->
// gemm (MFMA 3-term split scores, LDS-shared dbuf B tiles, 2-score exact
// top-2, fused compaction + gather + loss partials) -> cleanup (exact
// reference argmin for ~3% margin-flagged px, NB=2, grid 2048) -> loss.
// MARGIN 8e-5 (R14-25 validated). Exact-path arithmetic BIT-IDENTICAL to
// R0-R25 (passed, absmax 3.8e-6): pairwise-8 x_sq (contract off),
// d-ascending fp32 FMA chain, (xsq-2d)+esq, first-occurrence argmin.

#define KCODES 1024
#define DDIM   64
#define NPIX   65536
#define QELEMS 4194304
#define IDX_OFF (1 + QELEMS)
#define MARGIN 8e-5f
#define WT     2           // tiles per window (gemm)
#define NWIN   32          // 64 tiles / 2
#define NB     2           // pixels per cleanup chunk
#define NCLEAN 2048        // cleanup grid / dpart slots

typedef __attribute__((ext_vector_type(8))) short bf16x8;
typedef __attribute__((ext_vector_type(4))) float f32x4;

static __device__ __forceinline__ unsigned short f2bf(float f) {
    unsigned int u = __float_as_uint(f);
    unsigned int r = (u + 0x7FFFu + ((u >> 16) & 1u)) >> 16;   // RNE
    return (unsigned short)r;
}
static __device__ __forceinline__ float bf2f(unsigned short h) {
    return __uint_as_float(((unsigned int)h) << 16);
}

// ---------------- e prep v2: coalesced LDS-staged esq + bf16 split of (-2e) ----------------
// 64 blocks x 256 thr; block bk handles codes [bk*16, bk*16+16).
__global__ void __launch_bounds__(256) esplit_kernel(const float* __restrict__ e,
                                                     float* __restrict__ esq,
                                                     unsigned short* __restrict__ Eh,
                                                     unsigned short* __restrict__ El,
                                                     int* __restrict__ count,
                                                     float* __restrict__ dpart) {
    __shared__ float se[16][64];      // 4KB: 16 codes x 64 dims
    const int tid = threadIdx.x;
    const int bk = blockIdx.x;
    if (bk == 0) {
        if (tid == 0) *count = 0;
        for (int i = tid; i < NCLEAN; i += 256) dpart[i] = 0.f;  // ws poisoned; zero each call
    }

    // stage 16 codes = 4KB with one coalesced float4 per thread
    {
        const float4 v = *(const float4*)(e + (size_t)bk * 1024 + tid * 4);
        const int c = tid >> 4;
        const int d0 = (tid & 15) * 4;
        se[c][d0 + 0] = v.x;
        se[c][d0 + 1] = v.y;
        se[c][d0 + 2] = v.z;
        se[c][d0 + 3] = v.w;
    }
    __syncthreads();

    // esq: threads 0-15, EXACT numpy pairwise-8 from LDS copies (same order)
    if (tid < 16) {
#pragma clang fp contract(off)
        float r[8];
#pragma unroll
        for (int j = 0; j < 8; ++j) { float v = se[tid][j]; r[j] = v * v; }
#pragma unroll
        for (int i = 1; i < 8; ++i) {
#pragma unroll
            for (int j = 0; j < 8; ++j) { float v = se[tid][i * 8 + j]; r[j] += v * v; }
        }
        esq[bk * 16 + tid] = ((r[0] + r[1]) + (r[2] + r[3])) + ((r[4] + r[5]) + (r[6] + r[7]));
    }

    // split of (-2e): thread -> (code c, dchunk d0); packed 8B stores (coalesced)
    {
        const int c = tid >> 4;
        const int d0 = (tid & 15) * 4;
        unsigned short h[4], lo[4];
#pragma unroll
        for (int j = 0; j < 4; ++j) {
            float v = -2.0f * se[c][d0 + j];       // exact scaling
            h[j] = f2bf(v);
            lo[j] = f2bf(v - bf2f(h[j]));
        }
        const size_t off = (size_t)(bk * 16 + c) * DDIM + d0;
        *(ushort4*)(Eh + off) = make_ushort4(h[0], h[1], h[2], h[3]);
        *(ushort4*)(El + off) = make_ushort4(lo[0], lo[1], lo[2], lo[3]);
    }
}

// ---------------- MFMA scores + top-2 + fused compact + fused gather/loss ----------------
// Block = 256 thr = 4 waves; 64 px/block. 2-tile windows, 32 barriers.
// LDS 36.5KB -> 4 blocks/CU; grid 1024 = one packed round.
__global__ void __launch_bounds__(256, 4) gemm_kernel(const float* __restrict__ x,
                                                      const float* __restrict__ e,
                                                      const unsigned short* __restrict__ Eh,
                                                      const unsigned short* __restrict__ El,
                                                      const float* __restrict__ esq,
                                                      int* __restrict__ count,
                                                      int* __restrict__ list,
                                                      float* __restrict__ partial,
                                                      float* __restrict__ out) {
    __shared__ float x_lds[DDIM][64];              // 16KB
    __shared__ float esq_lds[KCODES];              // 4KB
    __shared__ unsigned char btile[2][WT][4096];   // 16KB dbuf window (per tile: Eh 2KB | El 2KB)
    __shared__ int sflag[64];
    __shared__ int sidx_l[64];

    const int tid = threadIdx.x;
    const int w = __builtin_amdgcn_readfirstlane(tid >> 6);
    const int l = tid & 63;
    const int g = l >> 4;              // 0..3
    const int col = l & 15;
    const int pxbase = blockIdx.x * 64;
    const int b = pxbase >> 10;
    const int p0 = pxbase & 1023;

    // stage x tile + esq
    {
        const float* xg = x + (size_t)b * 65536 + p0;
        for (int t = tid; t < DDIM * 64; t += 256)
            x_lds[t >> 6][t & 63] = xg[(size_t)(t >> 6) * 1024 + (t & 63)];
        for (int t = tid; t < KCODES; t += 256)
            esq_lds[t] = esq[t];
    }
    __syncthreads();

    // A fragments: row = col (px_local = w*16+col), k(d)-slot = g*8 + j (+32 per d-half)
    bf16x8 Ah0, Ah1, Al0, Al1;
    {
        const int pxl = w * 16 + col;
#pragma unroll
        for (int j = 0; j < 8; ++j) {
            float v0 = x_lds[g * 8 + j][pxl];
            unsigned short h0 = f2bf(v0);
            Ah0[j] = (short)h0;
            Al0[j] = (short)f2bf(v0 - bf2f(h0));
            float v1 = x_lds[32 + g * 8 + j][pxl];
            unsigned short h1 = f2bf(v1);
            Ah1[j] = (short)h1;
            Al1[j] = (short)f2bf(v1 - bf2f(h1));
        }
    }

    // B staging: thread covers 16B of each 4KB tile; 2 tiles per window.
    // swizzle: dchunk ^= (code&7)<<4 (bijective within each 128B code-row).
    const unsigned short* src_base = (tid < 128) ? Eh : El;
    const int u = tid & 127;
    const int code_w = u >> 3;
    const int dst_off = ((tid >> 7) << 11) + (code_w << 7)
                      + (((u & 7) << 4) ^ ((code_w & 7) << 4));
    float4 s0g, s1g;
    auto LDW = [&](int i) {    // load window i (tiles 2i, 2i+1)
        const char* sb = (const char*)src_base + (size_t)(2 * i) * 2048 + (size_t)u * 16;
        s0g = *(const float4*)(sb);
        s1g = *(const float4*)(sb + 2048);
    };
    auto STW = [&](int i) {
        *(float4*)&btile[i & 1][0][dst_off] = s0g;
        *(float4*)&btile[i & 1][1][dst_off] = s1g;
    };

    const int cx = (col & 7) << 4;
    const int rb = col << 7;
    const int oh0 = rb + ((g << 4) ^ cx);
    const int oh1 = rb + (((g << 4) + 64) ^ cx);

    float m1_0 = 3.4e38f, m1_1 = 3.4e38f, m1_2 = 3.4e38f, m1_3 = 3.4e38f;
    float m2_0 = 3.4e38f, m2_1 = 3.4e38f, m2_2 = 3.4e38f, m2_3 = 3.4e38f;
    int i1_0 = 0, i1_1 = 0, i1_2 = 0, i1_3 = 0;

    LDW(0); STW(0);    // window 0 staged (vmcnt auto before ds_write)
    LDW(1);            // window 1 in flight
    __syncthreads();

#pragma unroll 1
    for (int wn = 0; wn < NWIN; ++wn) {
        if (wn + 1 < NWIN) STW(wn + 1);   // buf (wn+1)&1: reads finished at last barrier
        if (wn + 2 < NWIN) LDW(wn + 2);

        const unsigned char* bw = &btile[wn & 1][0][0];
        const int kbase = wn * 32 + col;

        // 2 tiles, each a single 6-deep MFMA chain, acc seeded with esq.
        f32x4 t0, t1;
#define CHAIN(J, ACC)                                                          \
        {                                                                      \
            const unsigned char* bp_ = bw + (J) * 4096;                        \
            const bf16x8 Bh0 = *(const bf16x8*)(bp_ + oh0);                    \
            const bf16x8 Bh1 = *(const bf16x8*)(bp_ + oh1);                    \
            const bf16x8 Bl0 = *(const bf16x8*)(bp_ + 2048 + oh0);             \
            const bf16x8 Bl1 = *(const bf16x8*)(bp_ + 2048 + oh1);             \
            const float qe_ = esq_lds[kbase + (J) * 16];                       \
            ACC = (f32x4){qe_, qe_, qe_, qe_};                                 \
            ACC = __builtin_amdgcn_mfma_f32_16x16x32_bf16(Ah0, Bh0, ACC, 0, 0, 0); \
            ACC = __builtin_amdgcn_mfma_f32_16x16x32_bf16(Al0, Bh0, ACC, 0, 0, 0); \
            ACC = __builtin_amdgcn_mfma_f32_16x16x32_bf16(Ah0, Bl0, ACC, 0, 0, 0); \
            ACC = __builtin_amdgcn_mfma_f32_16x16x32_bf16(Ah1, Bh1, ACC, 0, 0, 0); \
            ACC = __builtin_amdgcn_mfma_f32_16x16x32_bf16(Al1, Bh1, ACC, 0, 0, 0); \
            ACC = __builtin_amdgcn_mfma_f32_16x16x32_bf16(Ah1, Bl1, ACC, 0, 0, 0); \
        }
        CHAIN(0, t0)
        CHAIN(1, t1)
#undef CHAIN

        // exact 2-score top2; ks ascending; strict-< => first-occurrence.
#define WTOP(R, M1, M2, I1)                                                    \
        {                                                                      \
            float s0_ = t0[R], s1_ = t1[R];                                    \
            float p01 = fminf(s0_, s1_), q01 = fmaxf(s0_, s1_);                \
            int i01 = (s1_ < s0_) ? kbase + 16 : kbase;                        \
            M2 = fminf(M2, fminf(q01, fmaxf(M1, p01)));                        \
            if (p01 < M1) I1 = i01;                                            \
            M1 = fminf(M1, p01);                                               \
        }
        WTOP(0, m1_0, m2_0, i1_0)
        WTOP(1, m1_1, m2_1, i1_1)
        WTOP(2, m1_2, m2_2, i1_2)
        WTOP(3, m1_3, m2_3, i1_3)
#undef WTOP
        __syncthreads();
    }

    // cross-lane merge over the 16 lanes of group g; record idx + flag in LDS
#define MERGE(M1, M2, I1, R)                                                   \
    {                                                                          \
        float a1_ = M1, a2_ = M2; int j1 = I1;                                 \
        _Pragma("unroll")                                                      \
        for (int off = 1; off < 16; off <<= 1) {                               \
            float b1 = __shfl_xor(a1_, off);                                   \
            int jb = __shfl_xor(j1, off);                                      \
            float b2 = __shfl_xor(a2_, off);                                   \
            float hi = fmaxf(a1_, b1);                                         \
            a2_ = fminf(fminf(a2_, b2), hi);                                   \
            if (b1 < a1_) j1 = jb;                                             \
            a1_ = fminf(a1_, b1);                                              \
        }                                                                      \
        if (col == 0) {                                                        \
            int pxl = w * 16 + g * 4 + (R);                                    \
            sflag[pxl] = (a2_ <= a1_ + MARGIN) ? 1 : 0;                        \
            sidx_l[pxl] = j1;                                                  \
        }                                                                      \
    }
    MERGE(m1_0, m2_0, i1_0, 0)
    MERGE(m1_1, m2_1, i1_1, 1)
    MERGE(m1_2, m2_2, i1_2, 2)
    MERGE(m1_3, m2_3, i1_3, 3)
#undef MERGE

    __syncthreads();

    // fused compaction + index output (coalesced)
    if (tid < 64) {
        out[IDX_OFF + pxbase + tid] = (float)sidx_l[tid];
        const bool f = sflag[tid] != 0;
        unsigned long long m = __ballot(f);
        int base = 0;
        if (l == 0 && m) base = atomicAdd(count, __popcll(m));
        base = __shfl(base, 0);
        if (f) {
            unsigned long long below = m & ((1ULL << l) - 1ULL);
            list[base + __popcll(below)] = pxbase + tid;
        }
    }

    // fused gather (quantized write) + loss partial (excludes flagged px)
    {
        const int px = tid & 63;
        const int dc = (tid >> 6) << 4;
        const int j1 = sidx_l[px];
        const bool fl = sflag[px] != 0;
        const float* er = e + (size_t)j1 * DDIM + dc;    // exact fp32 row (L2-hot)
        const float4 e0v = *(const float4*)(er);
        const float4 e1v = *(const float4*)(er + 4);
        const float4 e2v = *(const float4*)(er + 8);
        const float4 e3v = *(const float4*)(er + 12);
        float* ob = out + 1 + (((size_t)(b * 64 + dc)) << 10) + p0 + px;
        float acc = 0.f;
#define QW(VV, I0)                                                             \
        {                                                                      \
            ob[(size_t)(I0 + 0) << 10] = VV.x;                                 \
            ob[(size_t)(I0 + 1) << 10] = VV.y;                                 \
            ob[(size_t)(I0 + 2) << 10] = VV.z;                                 \
            ob[(size_t)(I0 + 3) << 10] = VV.w;                                 \
            float d0_ = VV.x - x_lds[dc + I0 + 0][px];                         \
            float d1_ = VV.y - x_lds[dc + I0 + 1][px];                         \
            float d2_ = VV.z - x_lds[dc + I0 + 2][px];                         \
            float d3_ = VV.w - x_lds[dc + I0 + 3][px];                         \
            acc = __builtin_fmaf(d0_, d0_, acc);                               \
            acc = __builtin_fmaf(d1_, d1_, acc);                               \
            acc = __builtin_fmaf(d2_, d2_, acc);                               \
            acc = __builtin_fmaf(d3_, d3_, acc);                               \
        }
        QW(e0v, 0)
        QW(e1v, 4)
        QW(e2v, 8)
        QW(e3v, 12)
#undef QW
        if (fl) acc = 0.f;
        __syncthreads();                 // all x_lds reads done before reuse as reduce buf
        float* red = &x_lds[0][0];
        red[tid] = acc;
        __syncthreads();
        for (int s = 128; s > 0; s >>= 1) {
            if (tid < s) red[tid] += red[tid + s];
            __syncthreads();
        }
        if (tid == 0) partial[blockIdx.x] = red[0];
    }
}

// ---------------- cleanup: exact argmin, NB=2 px/chunk, grid 2048 ----------------
__global__ void __launch_bounds__(256, 4) cleanup_kernel(const float* __restrict__ x,
                                                         const float* __restrict__ e,
                                                         const float* __restrict__ esq,
                                                         const int* __restrict__ count,
                                                         const int* __restrict__ list,
                                                         float* __restrict__ dpart,
                                                         float* __restrict__ out) {
    __shared__ float tile[DDIM][257];   // 65.8KB transpose tile
    __shared__ float xs[NB][68];
    __shared__ float xsqs[NB];
    __shared__ float rbest[4];
    __shared__ int   ridx[4];
    __shared__ int   plist[NB];
    __shared__ int   jsel;
    __shared__ float dacc;

    const int tid = threadIdx.x;
    const int cnt = *count;
    const int nchunk = (cnt + NB - 1) / NB;
    if (tid == 0) dacc = 0.f;

    for (int chunk = blockIdx.x; chunk < nchunk; chunk += gridDim.x) {
        const int base = chunk * NB;
        const int np = min(NB, cnt - base);      // block-uniform

        if (tid < np) plist[tid] = list[base + tid];
        __syncthreads();
        for (int q = tid; q < np * 64; q += 256) {
            const int pp = q >> 6, d = q & 63;
            const int p = plist[pp];
            xs[pp][d] = x[(size_t)(p >> 10) * 65536 + (size_t)d * 1024 + (p & 1023)];
        }
        __syncthreads();
        if (tid < np) {
#pragma clang fp contract(off)
            float r[8];
#pragma unroll
            for (int j = 0; j < 8; ++j) { float v = xs[tid][j]; r[j] = v * v; }
#pragma unroll
            for (int ii = 1; ii < 8; ++ii) {
#pragma unroll
                for (int j = 0; j < 8; ++j) { float v = xs[tid][ii * 8 + j]; r[j] += v * v; }
            }
            xsqs[tid] = ((r[0] + r[1]) + (r[2] + r[3])) + ((r[4] + r[5]) + (r[6] + r[7]));
        }

        float best[NB];
        int bidx[NB];
#pragma unroll
        for (int pp = 0; pp < NB; ++pp) { best[pp] = 3.4e38f; bidx[pp] = 0; }

#pragma unroll 1
        for (int T = 0; T < 4; ++T) {
            __syncthreads();
#pragma unroll
            for (int i = 0; i < 16; ++i) {
                const float4 v = *(const float4*)(e + (size_t)T * 16384 + (size_t)i * 1024 + tid * 4);
                const int c = 16 * i + (tid >> 4);
                const int d0 = (4 * tid) & 63;
                tile[d0 + 0][c] = v.x;
                tile[d0 + 1][c] = v.y;
                tile[d0 + 2][c] = v.z;
                tile[d0 + 3][c] = v.w;
            }
            __syncthreads();
            const float qe = esq[T * 256 + tid];
            const int kk = T * 256 + tid;
#pragma unroll
            for (int pp = 0; pp < NB; ++pp) {
                if (pp < np) {
                    float dt = 0.f;
#pragma unroll
                    for (int d = 0; d < DDIM; ++d)
                        dt = __builtin_fmaf(xs[pp][d], tile[d][tid], dt);
                    const float s = (xsqs[pp] - 2.0f * dt) + qe;
                    if (s < best[pp]) { best[pp] = s; bidx[pp] = kk; }
                }
            }
        }

#pragma unroll
        for (int pp = 0; pp < NB; ++pp) {
            if (pp < np) {
                const int p = plist[pp];
                float bb = best[pp];
                int bj = bidx[pp];
#pragma unroll
                for (int off = 1; off < 64; off <<= 1) {
                    float b2 = __shfl_xor(bb, off);
                    int k2 = __shfl_xor(bj, off);
                    if (b2 < bb || (b2 == bb && k2 < bj)) { bb = b2; bj = k2; }
                }
                if ((tid & 63) == 0) { rbest[tid >> 6] = bb; ridx[tid >> 6] = bj; }
                __syncthreads();
                if (tid == 0) {
                    float b0 = rbest[0]; int j0 = ridx[0];
#pragma unroll
                    for (int c2 = 1; c2 < 4; ++c2)
                        if (rbest[c2] < b0 || (rbest[c2] == b0 && ridx[c2] < j0)) {
                            b0 = rbest[c2]; j0 = ridx[c2];
                        }
                    jsel = j0;
                    out[IDX_OFF + p] = (float)j0;
                }
                __syncthreads();
                // patch quantized row + accumulate exact per-pixel contribution
                if (tid < 64) {
                    const int j0 = jsel;
                    const int d = tid;
                    const float ev = e[(size_t)j0 * DDIM + d];
                    const float xv = xs[pp][d];
                    out[1 + (((size_t)((p >> 10) * 64 + d)) << 10) + (p & 1023)] = ev;
                    float df = ev - xv;
                    float c = df * df;
#pragma unroll
                    for (int off = 1; off < 64; off <<= 1)
                        c += __shfl_xor(c, off);
                    if (tid == 0) dacc += c;
                }
                __syncthreads();
            }
        }
        __syncthreads();
    }
    if (tid == 0) dpart[blockIdx.x] = dacc;
}

// ---------------- deterministic loss finalize: 1024 partials + 2048 dparts ----------------
__global__ void __launch_bounds__(256) loss_kernel(const float* __restrict__ partial,
                                                   const float* __restrict__ dpart,
                                                   float* __restrict__ out) {
    float acc = 0.f;
    for (int i = threadIdx.x; i < 1024; i += 256) acc += partial[i];
    for (int i = threadIdx.x; i < NCLEAN; i += 256) acc += dpart[i];
    __shared__ float sm[256];
    sm[threadIdx.x] = acc;
    __syncthreads();
    for (int s = 128; s > 0; s >>= 1) {
        if (threadIdx.x < s) sm[threadIdx.x] += sm[threadIdx.x + s];
        __syncthreads();
    }
    // loss = q_latent + 0.25*e_latent = 1.25 * mean(diff^2)
    if (threadIdx.x == 0) out[0] = sm[0] * (1.25f / 4194304.f);
}

extern "C" void kernel_launch(void* const* d_in, const int* in_sizes, int n_in,
                              void* d_out, int out_size, void* d_ws, size_t ws_size,
                              hipStream_t stream) {
    const float* x = (const float*)d_in[0];   // [64,64,32,32]
    const float* e = (const float*)d_in[1];   // [1024,64]
    float* out = (float*)d_out;

    // ws: esq 4KB | Eh 128KB | El 128KB | count 4KB | list 256KB | partial 4KB | dpart 8KB
    char* wsb = (char*)d_ws;
    float*          esq     = (float*)wsb;
    unsigned short* Eh      = (unsigned short*)(wsb + 4096);
    unsigned short* El      = (unsigned short*)(wsb + 4096 + 131072);
    int*            count   = (int*)(wsb + 4096 + 2 * 131072);
    int*            list    = (int*)(wsb + 4096 + 2 * 131072 + 4096);
    float*          partial = (float*)(wsb + 4096 + 2 * 131072 + 4096 + NPIX * 4);
    float*          dpart   = (float*)(wsb + 4096 + 2 * 131072 + 4096 + NPIX * 4 + 4096);

    esplit_kernel<<<64, 256, 0, stream>>>(e, esq, Eh, El, count, dpart);
    gemm_kernel<<<NPIX / 64, 256, 0, stream>>>(x, e, Eh, El, esq, count, list, partial, out);
    cleanup_kernel<<<NCLEAN, 256, 0, stream>>>(x, e, esq, count, list, dpart, out);
    loss_kernel<<<1, 256, 0, stream>>>(partial, dpart, out);
}